// Round 10
// baseline (2073.689 us; speedup 1.0000x reference)
//
#include <hip/hip_runtime.h>
#include <hip/hip_bf16.h>

#define R_TOT  8192      // B*S
#define DIM    768       // D
#define FDICT  32768
#define TOPK   128
#define LN_EPS 1e-5f
#define BAND_M 0.12f
#define BAND_CAP 192

using f32x4  = __attribute__((ext_vector_type(4))) float;
using short8 = __attribute__((ext_vector_type(8))) short;

__device__ inline short f2bf(float f) {
    __hip_bfloat16 h = __float2bfloat16(f);
    return *reinterpret_cast<short*>(&h);
}
__device__ inline float bf2f(short s) {
    return __uint_as_float(((unsigned)(unsigned short)s) << 16);
}
__device__ inline void load_lds16(const void* g, void* l) {
    __builtin_amdgcn_global_load_lds(
        (const __attribute__((address_space(1))) unsigned int*)g,
        (__attribute__((address_space(3))) unsigned int*)l, 16, 0, 0);
}

// ---------------- K0: fp32 -> bf16 conversion (grid-stride, 16B stores) ---------
__global__ __launch_bounds__(256) void conv_bf16(
    const float* __restrict__ in, unsigned short* __restrict__ out, int n8)
{
    const int i0 = blockIdx.x * 256 + threadIdx.x;
    const int stride = gridDim.x * 256;
    for (int g = i0; g < n8; g += stride) {
        const float4 a = ((const float4*)in)[g * 2];
        const float4 b = ((const float4*)in)[g * 2 + 1];
        short8 v;
        v[0] = f2bf(a.x); v[1] = f2bf(a.y); v[2] = f2bf(a.z); v[3] = f2bf(a.w);
        v[4] = f2bf(b.x); v[5] = f2bf(b.y); v[6] = f2bf(b.z); v[7] = f2bf(b.w);
        ((short8*)out)[g] = v;
    }
}

// ---------------- K0b: max|gamma|, max|beta| -> gbmax[2] ------------------------
__global__ __launch_bounds__(256) void prep_gb(
    const float* __restrict__ gamma, const float* __restrict__ beta,
    float* __restrict__ gbmax)
{
    __shared__ float rg[4], rb[4];
    const int t = threadIdx.x;
    float g = 0.f, b = 0.f;
    for (int i = t; i < FDICT / 4; i += 256) {
        const float4 g4 = ((const float4*)gamma)[i];
        const float4 b4 = ((const float4*)beta)[i];
        g = fmaxf(g, fmaxf(fmaxf(fabsf(g4.x), fabsf(g4.y)),
                           fmaxf(fabsf(g4.z), fabsf(g4.w))));
        b = fmaxf(b, fmaxf(fmaxf(fabsf(b4.x), fabsf(b4.y)),
                           fmaxf(fabsf(b4.z), fabsf(b4.w))));
    }
#pragma unroll
    for (int o = 32; o > 0; o >>= 1) {
        g = fmaxf(g, __shfl_down(g, o, 64));
        b = fmaxf(b, __shfl_down(b, o, 64));
    }
    if ((t & 63) == 0) { rg[t >> 6] = g; rb[t >> 6] = b; }
    __syncthreads();
    if (t == 0) {
        gbmax[0] = fmaxf(fmaxf(rg[0], rg[1]), fmaxf(rg[2], rg[3]));
        gbmax[1] = fmaxf(fmaxf(rb[0], rb[1]), fmaxf(rb[2], rb[3]));
    }
}

// ---------------- K1: encoder GEMM — 256x256 tile, 8-wave, 4-phase/K-tile -------
#define READ_A(P)                                                              \
    af00 = *(const short8*)&Sb[abase + (2*(P))*1024 + sw0];                    \
    af01 = *(const short8*)&Sb[abase + (2*(P))*1024 + sw1];                    \
    af10 = *(const short8*)&Sb[abase + (2*(P)+1)*1024 + sw0];                  \
    af11 = *(const short8*)&Sb[abase + (2*(P)+1)*1024 + sw1];

#define DO_MFMA(P)                                                             \
    __builtin_amdgcn_s_setprio(1);                                             \
    _Pragma("unroll")                                                          \
    for (int n = 0; n < 4; ++n) {                                              \
        acc[2*(P)][n]   = __builtin_amdgcn_mfma_f32_16x16x32_bf16(af00, bf0[n], acc[2*(P)][n],   0,0,0); \
        acc[2*(P)][n]   = __builtin_amdgcn_mfma_f32_16x16x32_bf16(af01, bf1[n], acc[2*(P)][n],   0,0,0); \
        acc[2*(P)+1][n] = __builtin_amdgcn_mfma_f32_16x16x32_bf16(af10, bf0[n], acc[2*(P)+1][n], 0,0,0); \
        acc[2*(P)+1][n] = __builtin_amdgcn_mfma_f32_16x16x32_bf16(af11, bf1[n], acc[2*(P)+1][n], 0,0,0); \
    }                                                                          \
    __builtin_amdgcn_s_setprio(0);

__global__ __launch_bounds__(512, 2) void enc_gemm(
    const unsigned short* __restrict__ Xb, const unsigned short* __restrict__ Wb,
    const float* __restrict__ benc, unsigned short* __restrict__ Zb)
{
    __shared__ __align__(16) unsigned short S[65536];   // 128 KiB: 2 bufs x (A|B)

    const int t = threadIdx.x;
    const int w = t >> 6, l = t & 63;

    const int cpx = (int)gridDim.x >> 3;
    const int swz = ((int)blockIdx.x & 7) * cpx + ((int)blockIdx.x >> 3);
    const long bm = (long)(swz >> 7) * 256;
    const long bn = (long)(swz & 127) * 256;

    const int wm = w >> 2, wn = w & 3;
    const int lrow = l & 15, l4 = l >> 4;

    const int sw0 = ((l4     ) ^ (lrow & 7)) * 8;
    const int sw1 = ((4 + l4 ) ^ (lrow & 7)) * 8;
    const int abase = wm * 8192 + lrow * 64;
    const int bbase = 16384 + wn * 4096 + lrow * 64;

    const int rh0 = w * 16 + (l >> 3);
    const int rh1 = rh0 + 8;
    const int gsl = ((l & 7) ^ (l >> 3)) * 8;
    const unsigned short* pA00 = Xb + (bm +       rh0) * DIM + gsl;
    const unsigned short* pA01 = Xb + (bm +       rh1) * DIM + gsl;
    const unsigned short* pA10 = Xb + (bm + 128 + rh0) * DIM + gsl;
    const unsigned short* pA11 = Xb + (bm + 128 + rh1) * DIM + gsl;
    const unsigned short* pB00 = Wb + (bn +       rh0) * DIM + gsl;
    const unsigned short* pB01 = Wb + (bn +       rh1) * DIM + gsl;
    const unsigned short* pB10 = Wb + (bn + 128 + rh0) * DIM + gsl;
    const unsigned short* pB11 = Wb + (bn + 128 + rh1) * DIM + gsl;
    const int d00 = w * 1024;
    const int d01 = w * 1024 + 512;

    f32x4 acc[8][4];
#pragma unroll
    for (int m = 0; m < 8; ++m)
#pragma unroll
        for (int n = 0; n < 4; ++n) acc[m][n] = (f32x4){0.f, 0.f, 0.f, 0.f};

    load_lds16(pA00, S + d00);
    load_lds16(pA01, S + d01);
    load_lds16(pA10, S + 8192 + d00);
    load_lds16(pA11, S + 8192 + d01);
    load_lds16(pB00, S + 16384 + d00);
    load_lds16(pB01, S + 16384 + d01);
    load_lds16(pB10, S + 16384 + 8192 + d00);
    load_lds16(pB11, S + 16384 + 8192 + d01);
    pA00 += 64; pA01 += 64; pA10 += 64; pA11 += 64;
    pB00 += 64; pB01 += 64; pB10 += 64; pB11 += 64;

    short8 bf0[4], bf1[4];
    short8 af00, af01, af10, af11;

#pragma unroll 1
    for (int kt = 0; kt < 12; ++kt) {
        const unsigned short* Sb = S + (kt & 1) * 32768;
        unsigned short*       Sn = S + ((kt & 1) ^ 1) * 32768;

        if (kt < 11) {
            load_lds16(pA00, Sn + d00);
            load_lds16(pA01, Sn + d01);
            load_lds16(pA10, Sn + 8192 + d00);
            load_lds16(pA11, Sn + 8192 + d01);
            asm volatile("s_waitcnt vmcnt(4)" ::: "memory");
        } else {
            asm volatile("s_waitcnt vmcnt(0)" ::: "memory");
        }
        __builtin_amdgcn_s_barrier();
#pragma unroll
        for (int n = 0; n < 4; ++n) {
            bf0[n] = *(const short8*)&Sb[bbase + n * 1024 + sw0];
            bf1[n] = *(const short8*)&Sb[bbase + n * 1024 + sw1];
        }
        READ_A(0)
        DO_MFMA(0)
        asm volatile("" ::: "memory");
        __builtin_amdgcn_s_barrier();

        READ_A(1)
        if (kt < 11) {
            load_lds16(pB00, Sn + 16384 + d00);
            load_lds16(pB01, Sn + 16384 + d01);
            load_lds16(pB10, Sn + 16384 + 8192 + d00);
            load_lds16(pB11, Sn + 16384 + 8192 + d01);
        }
        asm volatile("" ::: "memory");
        __builtin_amdgcn_s_barrier();
        DO_MFMA(1)
        asm volatile("" ::: "memory");
        __builtin_amdgcn_s_barrier();

        READ_A(2)
        asm volatile("" ::: "memory");
        __builtin_amdgcn_s_barrier();
        DO_MFMA(2)
        asm volatile("" ::: "memory");
        __builtin_amdgcn_s_barrier();

        READ_A(3)
        asm volatile("" ::: "memory");
        __builtin_amdgcn_s_barrier();
        DO_MFMA(3)
        asm volatile("" ::: "memory");
        __builtin_amdgcn_s_barrier();

        pA00 += 64; pA01 += 64; pA10 += 64; pA11 += 64;
        pB00 += 64; pB01 += 64; pB10 += 64; pB11 += 64;
    }

    __syncthreads();
    float bias[4];
#pragma unroll
    for (int n = 0; n < 4; ++n) bias[n] = benc[bn + wn * 64 + n * 16 + lrow];
    unsigned short* Cs = S;
#pragma unroll
    for (int m = 0; m < 8; ++m)
#pragma unroll
        for (int n = 0; n < 4; ++n)
#pragma unroll
            for (int q = 0; q < 4; ++q)
                Cs[(wm * 128 + m * 16 + l4 * 4 + q) * 256 + wn * 64 + n * 16 + lrow] =
                    (unsigned short)f2bf(acc[m][n][q] + bias[n]);
    __syncthreads();
#pragma unroll
    for (int it = 0; it < 16; ++it) {
        const int g = t + it * 512;
        const int row = g >> 5;
        const int c8 = (g & 31) * 8;
        const short8 v = *(const short8*)&Cs[row * 256 + c8];
        __builtin_nontemporal_store(v, (short8*)&Zb[(bm + row) * FDICT + bn + c8]);
    }
}

// ---------------- K2: stats + LN + coarse/fine threshold + classify -------------
// 5 barriers total. Zero-fill of the feature row is issued at the KERNEL TAIL
// (after the last barrier) so no barrier vmcnt(0)-drain stalls on the 1 GB
// write stream; value scatter is deferred to refine_select (cross-kernel order).
__global__ __launch_bounds__(1024) void topk_select(
    const unsigned short* __restrict__ Zb, const float* __restrict__ gamma,
    const float* __restrict__ beta, const float* __restrict__ gbmax,
    int* __restrict__ sel_idx, float* __restrict__ sel_val,
    int* __restrict__ band_idx, int* __restrict__ cdef, int* __restrict__ nband,
    float* __restrict__ muarr, float* __restrict__ sinvarr,
    float* __restrict__ feat)
{
    __shared__ float    redf[64];     // [4][16]: sum, sumsq, zmax, zmin
    __shared__ unsigned cc[12];       // 4 coarse + 4 fine0 + 4 fine1 (u16-packed)
    __shared__ unsigned scomp[2];

    const int t = threadIdx.x;
    const int w = t >> 6;
    const long r = blockIdx.x;

    if (t < 12) cc[t] = 0u;
    if (t == 12) { scomp[0] = 0u; scomp[1] = 0u; }

    const float gA = gbmax[0], bA = gbmax[1];

    unsigned u[32];
    float sum = 0.f, sumsq = 0.f, zmx = -1e30f, zmn = 1e30f;
    const short8* Z8 = (const short8*)(Zb + r * (size_t)FDICT);
#pragma unroll
    for (int q = 0; q < 4; ++q) {
        const short8 v = Z8[q * 1024 + t];
#pragma unroll
        for (int j = 0; j < 8; ++j) {
            const float f = bf2f(v[j]);
            u[q * 8 + j] = __float_as_uint(f);
            sum += f; sumsq += f * f;
            zmx = fmaxf(zmx, f); zmn = fminf(zmn, f);
        }
    }
#pragma unroll
    for (int o = 32; o > 0; o >>= 1) {
        sum   += __shfl_down(sum, o, 64);
        sumsq += __shfl_down(sumsq, o, 64);
        zmx = fmaxf(zmx, __shfl_down(zmx, o, 64));
        zmn = fminf(zmn, __shfl_down(zmn, o, 64));
    }
    if ((t & 63) == 0) {
        redf[w] = sum; redf[16 + w] = sumsq; redf[32 + w] = zmx; redf[48 + w] = zmn;
    }
    __syncthreads();                                      // B1
    float s_ = 0.f, sq_ = 0.f, mx_ = -1e30f, mn_ = 1e30f;
#pragma unroll
    for (int i = 0; i < 16; ++i) {
        s_ += redf[i]; sq_ += redf[16 + i];
        mx_ = fmaxf(mx_, redf[32 + i]); mn_ = fminf(mn_, redf[48 + i]);
    }
    const float mu = s_ / (float)FDICT;
    float var = sq_ / (float)FDICT - mu * mu;
    if (var < 0.f) var = 0.f;
    const float sinv = 1.f / sqrtf(var + LN_EPS);
    // upper bound on any a = relu((z-mu)*sinv*g + b):
    const float hi0 = fmaxf(mx_ - mu, mu - mn_) * sinv * gA + bA + 1e-3f;

    // normalize in registers
#pragma unroll
    for (int q = 0; q < 4; ++q) {
        const size_t base = (size_t)(q * 1024 + t) * 8;
        const float4 g0 = *(const float4*)(gamma + base);
        const float4 g1 = *(const float4*)(gamma + base + 4);
        const float4 b0 = *(const float4*)(beta + base);
        const float4 b1 = *(const float4*)(beta + base + 4);
        const float gs[8] = {g0.x, g0.y, g0.z, g0.w, g1.x, g1.y, g1.z, g1.w};
        const float bs[8] = {b0.x, b0.y, b0.z, b0.w, b1.x, b1.y, b1.z, b1.w};
#pragma unroll
        for (int j = 0; j < 8; ++j) {
            const int i = q * 8 + j;
            u[i] = __float_as_uint(fmaxf(
                fmaf((__uint_as_float(u[i]) - mu) * sinv, gs[j], bs[j]), 0.f));
        }
    }

    // ---- coarse: 8 buckets over [0, hi0) ----
    const float inv8 = 8.f / hi0;
    int c[7];
#pragma unroll
    for (int j = 0; j < 7; ++j) c[j] = 0;
#pragma unroll
    for (int i = 0; i < 32; ++i) {
        const float a = __uint_as_float(u[i]);
        int b = (int)(a * inv8); b = b > 7 ? 7 : b;
#pragma unroll
        for (int j = 0; j < 7; ++j) c[j] += (b > j);
    }
    {
        unsigned pk[4];
        pk[0] = (unsigned)c[0] | ((unsigned)c[1] << 16);
        pk[1] = (unsigned)c[2] | ((unsigned)c[3] << 16);
        pk[2] = (unsigned)c[4] | ((unsigned)c[5] << 16);
        pk[3] = (unsigned)c[6];
#pragma unroll
        for (int o = 32; o > 0; o >>= 1)
#pragma unroll
            for (int m = 0; m < 4; ++m) pk[m] += __shfl_down(pk[m], o, 64);
        if ((t & 63) == 0)
#pragma unroll
            for (int m = 0; m < 4; ++m) atomicAdd(&cc[m], pk[m]);
    }
    __syncthreads();                                      // B2
    int J = -1;
#pragma unroll
    for (int j = 0; j < 7; ++j) {
        const unsigned cj = (cc[j >> 1] >> ((j & 1) * 16)) & 0xFFFFu;
        J += (cj >= TOPK);
    }
    float lo = (float)(J + 1) * (hi0 * 0.125f);
    float width = hi0 * 0.125f;

    // ---- two fine rounds: 7 thresholds each, width /= 8 per round ----
#pragma unroll 1
    for (int pass = 0; pass < 2; ++pass) {
        const float st = width * 0.125f;
        float s[7];
#pragma unroll
        for (int k = 0; k < 7; ++k) s[k] = lo + (float)(k + 1) * st;
        int f[7];
#pragma unroll
        for (int k = 0; k < 7; ++k) f[k] = 0;
#pragma unroll
        for (int i = 0; i < 32; ++i) {
            const float a = __uint_as_float(u[i]);
#pragma unroll
            for (int k = 0; k < 7; ++k) f[k] += (a > s[k]);
        }
        unsigned fp[4];
        fp[0] = (unsigned)f[0] | ((unsigned)f[1] << 16);
        fp[1] = (unsigned)f[2] | ((unsigned)f[3] << 16);
        fp[2] = (unsigned)f[4] | ((unsigned)f[5] << 16);
        fp[3] = (unsigned)f[6];
#pragma unroll
        for (int o = 32; o > 0; o >>= 1)
#pragma unroll
            for (int m = 0; m < 4; ++m) fp[m] += __shfl_down(fp[m], o, 64);
        if ((t & 63) == 0)
#pragma unroll
            for (int m = 0; m < 4; ++m) atomicAdd(&cc[4 + pass * 4 + m], fp[m]);
        __syncthreads();                                  // B3 / B4
        int K = 0;
#pragma unroll
        for (int k = 0; k < 7; ++k) {
            const unsigned fk = (cc[4 + pass * 4 + (k >> 1)] >> ((k & 1) * 16)) & 0xFFFFu;
            K += (fk >= TOPK);
        }
        lo += (float)K * st;
        width = st;
    }
    const float Tf = lo + 0.5f * width;   // |Tf - V128| <= hi0/1024 + ulp
    const float thi = Tf + BAND_M, tlo = Tf - BAND_M;

    // classify (values only; feat scatter deferred to refine_select)
#pragma unroll
    for (int i = 0; i < 32; ++i) {
        const float a = __uint_as_float(u[i]);
        const int idx = ((i >> 3) * 1024 + t) * 8 + (i & 7);
        if (a > thi) {
            const unsigned s2 = atomicAdd(&scomp[0], 1u);
            sel_idx[r * TOPK + s2] = idx;
            sel_val[r * TOPK + s2] = a;
        } else if (a >= tlo) {
            const unsigned s2 = atomicAdd(&scomp[1], 1u);
            if (s2 < BAND_CAP) band_idx[r * BAND_CAP + s2] = idx;
        }
    }
    __syncthreads();                                      // B5 (last barrier)
    if (t == 0) {
        cdef[r]  = (int)scomp[0];
        int nb = (int)scomp[1]; if (nb > BAND_CAP) nb = BAND_CAP;
        nband[r] = nb;
        muarr[r] = mu; sinvarr[r] = sinv;
    }
    // tail: zero the feature row; no barrier follows -> retires asynchronously
    if (feat) {
        const f32x4 z4 = (f32x4){0.f, 0.f, 0.f, 0.f};
        f32x4* row4 = (f32x4*)(feat + r * (size_t)FDICT);
#pragma unroll
        for (int q = 0; q < 8; ++q)
            __builtin_nontemporal_store(z4, &row4[q * 1024 + t]);
    }
}

// ---------------- K2b: fp64 refinement + final select + feat scatter ------------
__global__ __launch_bounds__(256) void refine_select(
    const float* __restrict__ X, const float* __restrict__ Wenc,
    const float* __restrict__ benc, const float* __restrict__ gamma,
    const float* __restrict__ beta, const int* __restrict__ band_idx,
    const int* __restrict__ cdef, const int* __restrict__ nband,
    const float* __restrict__ muarr, const float* __restrict__ sinvarr,
    int* __restrict__ sel_idx, float* __restrict__ sel_val,
    float* __restrict__ feat)
{
    __shared__ float xs[DIM];
    __shared__ float cval[BAND_CAP];
    __shared__ int   cidx[BAND_CAP];
    __shared__ int   scnt;
    const int t = threadIdx.x;
    const long r = blockIdx.x;
    const int w = t >> 6, l = t & 63;

    for (int i = t; i < DIM; i += 256) xs[i] = X[r * DIM + i];
    if (t == 0) scnt = 0;
    const int nb = nband[r];
    const int cd = cdef[r];
    int need = TOPK - cd; if (need > nb) need = nb;
    const double mu = (double)muarr[r], sinv = (double)sinvarr[r];

    // scatter the definite-in values (zeros were written by topk's tail;
    // kernel boundary orders them before us)
    if (feat && t < cd)
        feat[r * (size_t)FDICT + sel_idx[r * TOPK + t]] = sel_val[r * TOPK + t];
    __syncthreads();

    for (int c = w; c < nb; c += 4) {
        const int fi = band_idx[r * BAND_CAP + c];
        const float* wr = Wenc + (size_t)fi * DIM;
        double s = 0.0;
        for (int k = l; k < DIM; k += 64) s = fma((double)xs[k], (double)wr[k], s);
#pragma unroll
        for (int o = 32; o > 0; o >>= 1) s += __shfl_down(s, o, 64);
        if (l == 0) {
            const double z = s + (double)benc[fi];
            const double a = (z - mu) * sinv * (double)gamma[fi] + (double)beta[fi];
            cval[c] = fmaxf((float)a, 0.f);
            cidx[c] = fi;
        }
    }
    __syncthreads();
    if (t < nb) {
        const float v = cval[t];
        const int id = cidx[t];
        int rank = 0;
        for (int j = 0; j < nb; ++j) {
            const float vj = cval[j];
            rank += (vj > v) || (vj == v && cidx[j] < id);
        }
        if (rank < need) {
            const int s = atomicAdd(&scnt, 1);
            sel_idx[r * TOPK + cd + s] = id;
            sel_val[r * TOPK + cd + s] = v;
            if (feat) feat[r * (size_t)FDICT + id] = v;
        }
    }
}

// ---------------- K3: transpose W_dec [768][32768] -> WdTb [32768][768] bf16 ----
__global__ __launch_bounds__(256) void transposeWd(
    const float* __restrict__ Wd, unsigned short* __restrict__ WdTb)
{
    __shared__ float tile[32][33];
    const int fx = blockIdx.x * 32;
    const int dy = blockIdx.y * 32;
    const int tx = threadIdx.x & 31;
    const int ty = threadIdx.x >> 5;
    for (int i = ty; i < 32; i += 8)
        tile[i][tx] = Wd[(size_t)(dy + i) * FDICT + fx + tx];
    __syncthreads();
    for (int i = ty; i < 32; i += 8)
        WdTb[(size_t)(fx + i) * DIM + dy + tx] = (unsigned short)f2bf(tile[tx][i]);
}

// ---------------- K4: sparse decode (bf16 W_decT, fp32 math) --------------------
__global__ __launch_bounds__(384) void decode(
    const int* __restrict__ sel_idx, const float* __restrict__ sel_val,
    const unsigned short* __restrict__ WdTb, const float* __restrict__ bdec,
    float* __restrict__ out)
{
    __shared__ int   sidx[TOPK];
    __shared__ float sval[TOPK];
    const int t = threadIdx.x;
    const long r = blockIdx.x;
    if (t < TOPK) { sidx[t] = sel_idx[r * TOPK + t]; sval[t] = sel_val[r * TOPK + t]; }
    __syncthreads();
    const float2 b2 = *(const float2*)(bdec + t * 2);
    float a0 = b2.x, a1 = b2.y;
    for (int j = 0; j < TOPK; ++j) {
        const unsigned wp = *(const unsigned*)(WdTb + (size_t)sidx[j] * DIM + t * 2);
        const float v = sval[j];
        a0 = fmaf(v, __uint_as_float((wp & 0xFFFFu) << 16), a0);
        a1 = fmaf(v, __uint_as_float(wp & 0xFFFF0000u), a1);
    }
    float2 o2; o2.x = a0; o2.y = a1;
    *(float2*)(out + r * DIM + t * 2) = o2;
}

// ---------------- K5 (fallback only): zero rows + scatter -----------------------
__global__ __launch_bounds__(1024) void featfill(
    const int* __restrict__ sel_idx, const float* __restrict__ sel_val,
    float* __restrict__ feat)
{
    const int t = threadIdx.x;
    const long r = blockIdx.x;
    const f32x4 z4 = (f32x4){0.f, 0.f, 0.f, 0.f};
    f32x4* row4 = (f32x4*)(feat + r * FDICT);
    for (int i = t; i < FDICT / 4; i += 1024)
        __builtin_nontemporal_store(z4, &row4[i]);
    __syncthreads();
    if (t < TOPK)
        feat[r * FDICT + sel_idx[r * TOPK + t]] = sel_val[r * TOPK + t];
}

extern "C" void kernel_launch(void* const* d_in, const int* in_sizes, int n_in,
                              void* d_out, int out_size, void* d_ws, size_t ws_size,
                              hipStream_t stream)
{
    const float* x     = (const float*)d_in[0];
    const float* Wenc  = (const float*)d_in[1];
    const float* benc  = (const float*)d_in[2];
    const float* gamma = (const float*)d_in[3];
    const float* beta  = (const float*)d_in[4];
    const float* Wdec  = (const float*)d_in[5];
    const float* bdec  = (const float*)d_in[6];

    float* out  = (float*)d_out;                      // [8192*768] fp32
    float* feat = out + (size_t)R_TOT * DIM;          // [8192*32768] fp32 region

    unsigned short* Xb = (unsigned short*)out;        // 12.6 MB (dead until decode)

    char* ws = (char*)d_ws;
    int*   sidx  = (int*)ws;                                        // 4 MB
    float* sval  = (float*)(ws + (size_t)R_TOT * TOPK * 4);         // 4 MB
    int*   bidx  = (int*)(ws + (size_t)R_TOT * TOPK * 8);           // 6.3 MB
    int*   cdef  = (int*)(ws + (size_t)R_TOT * (TOPK * 8 + BAND_CAP * 4));
    int*   nbnd  = cdef + R_TOT;
    float* muarr = (float*)(nbnd + R_TOT);
    float* sinva = muarr + R_TOT;
    float* gbmax = sinva + R_TOT;                                   // 2 floats

    // big-workspace path: Zb/Wb/WdTb live in ws -> feat region free during topk
    const size_t WS_NEED = 624ull << 20;
    const bool big = (ws_size >= WS_NEED);

    unsigned short* Zb, *Wb, *WdTb;
    if (big) {
        Zb   = (unsigned short*)(ws + (16ull << 20));
        Wb   = (unsigned short*)(ws + (528ull << 20));
        WdTb = (unsigned short*)(ws + (576ull << 20));
    } else {
        Zb   = (unsigned short*)feat;                            // 537 MB
        Wb   = (unsigned short*)((char*)feat + 536870912ull);    // 50.3 MB
        WdTb = (unsigned short*)((char*)feat + 587202560ull);    // 50.3 MB
    }
    float* featArg = big ? feat : nullptr;

    prep_gb<<<1, 256, 0, stream>>>(gamma, beta, gbmax);
    conv_bf16<<<1536, 256, 0, stream>>>(x,    Xb, R_TOT * DIM / 8);
    conv_bf16<<<2048, 256, 0, stream>>>(Wenc, Wb, FDICT * DIM / 8);
    enc_gemm<<<4096, 512, 0, stream>>>(Xb, Wb, benc, Zb);
    topk_select<<<R_TOT, 1024, 0, stream>>>(Zb, gamma, beta, gbmax,
                                            sidx, sval, bidx, cdef, nbnd,
                                            muarr, sinva, featArg);
    refine_select<<<R_TOT, 256, 0, stream>>>(x, Wenc, benc, gamma, beta,
                                             bidx, cdef, nbnd, muarr, sinva,
                                             sidx, sval, featArg);
    transposeWd<<<dim3(FDICT / 32, DIM / 32), 256, 0, stream>>>(Wdec, WdTb);
    decode<<<R_TOT, 384, 0, stream>>>(sidx, sval, WdTb, bdec, out);
    if (!big)
        featfill<<<R_TOT, 1024, 0, stream>>>(sidx, sval, feat);
}

// Round 11
// 1789.684 us; speedup vs baseline: 1.1587x; 1.1587x over previous
//
#include <hip/hip_runtime.h>
#include <hip/hip_bf16.h>

#define R_TOT  8192      // B*S
#define DIM    768       // D
#define FDICT  32768
#define TOPK   128
#define LN_EPS 1e-5f
#define BAND_M 0.12f
#define BAND_CAP 192

using f32x4  = __attribute__((ext_vector_type(4))) float;
using short8 = __attribute__((ext_vector_type(8))) short;

__device__ inline short f2bf(float f) {
    __hip_bfloat16 h = __float2bfloat16(f);
    return *reinterpret_cast<short*>(&h);
}
__device__ inline float bf2f(short s) {
    return __uint_as_float(((unsigned)(unsigned short)s) << 16);
}
__device__ inline void load_lds16(const void* g, void* l) {
    __builtin_amdgcn_global_load_lds(
        (const __attribute__((address_space(1))) unsigned int*)g,
        (__attribute__((address_space(3))) unsigned int*)l, 16, 0, 0);
}

// ---------------- K0: fp32 -> bf16 conversion (grid-stride, 16B stores) ---------
__global__ __launch_bounds__(256) void conv_bf16(
    const float* __restrict__ in, unsigned short* __restrict__ out, int n8)
{
    const int i0 = blockIdx.x * 256 + threadIdx.x;
    const int stride = gridDim.x * 256;
    for (int g = i0; g < n8; g += stride) {
        const float4 a = ((const float4*)in)[g * 2];
        const float4 b = ((const float4*)in)[g * 2 + 1];
        short8 v;
        v[0] = f2bf(a.x); v[1] = f2bf(a.y); v[2] = f2bf(a.z); v[3] = f2bf(a.w);
        v[4] = f2bf(b.x); v[5] = f2bf(b.y); v[6] = f2bf(b.z); v[7] = f2bf(b.w);
        ((short8*)out)[g] = v;
    }
}

// ---------------- K0b: gamma/beta info: |g|max, |b|max, uniform?, g0, b0 --------
__global__ __launch_bounds__(256) void prep_gb(
    const float* __restrict__ gamma, const float* __restrict__ beta,
    float* __restrict__ gbinfo)
{
    __shared__ float rr[16];
    const int t = threadIdx.x;
    const int w = t >> 6;
    float gmn = 1e30f, gmx = -1e30f, bmn = 1e30f, bmx = -1e30f;
    for (int i = t; i < FDICT / 4; i += 256) {
        const float4 g4 = ((const float4*)gamma)[i];
        const float4 b4 = ((const float4*)beta)[i];
        gmn = fminf(gmn, fminf(fminf(g4.x, g4.y), fminf(g4.z, g4.w)));
        gmx = fmaxf(gmx, fmaxf(fmaxf(g4.x, g4.y), fmaxf(g4.z, g4.w)));
        bmn = fminf(bmn, fminf(fminf(b4.x, b4.y), fminf(b4.z, b4.w)));
        bmx = fmaxf(bmx, fmaxf(fmaxf(b4.x, b4.y), fmaxf(b4.z, b4.w)));
    }
#pragma unroll
    for (int o = 32; o > 0; o >>= 1) {
        gmn = fminf(gmn, __shfl_down(gmn, o, 64));
        gmx = fmaxf(gmx, __shfl_down(gmx, o, 64));
        bmn = fminf(bmn, __shfl_down(bmn, o, 64));
        bmx = fmaxf(bmx, __shfl_down(bmx, o, 64));
    }
    if ((t & 63) == 0) {
        rr[w * 4 + 0] = gmn; rr[w * 4 + 1] = gmx;
        rr[w * 4 + 2] = bmn; rr[w * 4 + 3] = bmx;
    }
    __syncthreads();
    if (t == 0) {
        float a = rr[0], b = rr[1], c = rr[2], d = rr[3];
        for (int i = 1; i < 4; ++i) {
            a = fminf(a, rr[i * 4 + 0]); b = fmaxf(b, rr[i * 4 + 1]);
            c = fminf(c, rr[i * 4 + 2]); d = fmaxf(d, rr[i * 4 + 3]);
        }
        gbinfo[0] = fmaxf(fabsf(a), fabsf(b));            // |gamma| max
        gbinfo[1] = fmaxf(fabsf(c), fabsf(d));            // |beta| max
        gbinfo[2] = (a == b && c == d) ? 1.f : 0.f;       // uniform?
        gbinfo[3] = b;                                    // g0
        gbinfo[4] = d;                                    // b0
    }
}

// ---------------- K1: encoder GEMM — 256x256 tile, 8-wave, 4-phase/K-tile -------
#define READ_A(P)                                                              \
    af00 = *(const short8*)&Sb[abase + (2*(P))*1024 + sw0];                    \
    af01 = *(const short8*)&Sb[abase + (2*(P))*1024 + sw1];                    \
    af10 = *(const short8*)&Sb[abase + (2*(P)+1)*1024 + sw0];                  \
    af11 = *(const short8*)&Sb[abase + (2*(P)+1)*1024 + sw1];

#define DO_MFMA(P)                                                             \
    __builtin_amdgcn_s_setprio(1);                                             \
    _Pragma("unroll")                                                          \
    for (int n = 0; n < 4; ++n) {                                              \
        acc[2*(P)][n]   = __builtin_amdgcn_mfma_f32_16x16x32_bf16(af00, bf0[n], acc[2*(P)][n],   0,0,0); \
        acc[2*(P)][n]   = __builtin_amdgcn_mfma_f32_16x16x32_bf16(af01, bf1[n], acc[2*(P)][n],   0,0,0); \
        acc[2*(P)+1][n] = __builtin_amdgcn_mfma_f32_16x16x32_bf16(af10, bf0[n], acc[2*(P)+1][n], 0,0,0); \
        acc[2*(P)+1][n] = __builtin_amdgcn_mfma_f32_16x16x32_bf16(af11, bf1[n], acc[2*(P)+1][n], 0,0,0); \
    }                                                                          \
    __builtin_amdgcn_s_setprio(0);

__global__ __launch_bounds__(512, 2) void enc_gemm(
    const unsigned short* __restrict__ Xb, const unsigned short* __restrict__ Wb,
    const float* __restrict__ benc, unsigned short* __restrict__ Zb)
{
    __shared__ __align__(16) unsigned short S[65536];   // 128 KiB: 2 bufs x (A|B)

    const int t = threadIdx.x;
    const int w = t >> 6, l = t & 63;

    const int cpx = (int)gridDim.x >> 3;
    const int swz = ((int)blockIdx.x & 7) * cpx + ((int)blockIdx.x >> 3);
    const long bm = (long)(swz >> 7) * 256;
    const long bn = (long)(swz & 127) * 256;

    const int wm = w >> 2, wn = w & 3;
    const int lrow = l & 15, l4 = l >> 4;

    const int sw0 = ((l4     ) ^ (lrow & 7)) * 8;
    const int sw1 = ((4 + l4 ) ^ (lrow & 7)) * 8;
    const int abase = wm * 8192 + lrow * 64;
    const int bbase = 16384 + wn * 4096 + lrow * 64;

    const int rh0 = w * 16 + (l >> 3);
    const int rh1 = rh0 + 8;
    const int gsl = ((l & 7) ^ (l >> 3)) * 8;
    const unsigned short* pA00 = Xb + (bm +       rh0) * DIM + gsl;
    const unsigned short* pA01 = Xb + (bm +       rh1) * DIM + gsl;
    const unsigned short* pA10 = Xb + (bm + 128 + rh0) * DIM + gsl;
    const unsigned short* pA11 = Xb + (bm + 128 + rh1) * DIM + gsl;
    const unsigned short* pB00 = Wb + (bn +       rh0) * DIM + gsl;
    const unsigned short* pB01 = Wb + (bn +       rh1) * DIM + gsl;
    const unsigned short* pB10 = Wb + (bn + 128 + rh0) * DIM + gsl;
    const unsigned short* pB11 = Wb + (bn + 128 + rh1) * DIM + gsl;
    const int d00 = w * 1024;
    const int d01 = w * 1024 + 512;

    f32x4 acc[8][4];
#pragma unroll
    for (int m = 0; m < 8; ++m)
#pragma unroll
        for (int n = 0; n < 4; ++n) acc[m][n] = (f32x4){0.f, 0.f, 0.f, 0.f};

    load_lds16(pA00, S + d00);
    load_lds16(pA01, S + d01);
    load_lds16(pA10, S + 8192 + d00);
    load_lds16(pA11, S + 8192 + d01);
    load_lds16(pB00, S + 16384 + d00);
    load_lds16(pB01, S + 16384 + d01);
    load_lds16(pB10, S + 16384 + 8192 + d00);
    load_lds16(pB11, S + 16384 + 8192 + d01);
    pA00 += 64; pA01 += 64; pA10 += 64; pA11 += 64;
    pB00 += 64; pB01 += 64; pB10 += 64; pB11 += 64;

    short8 bf0[4], bf1[4];
    short8 af00, af01, af10, af11;

#pragma unroll 1
    for (int kt = 0; kt < 12; ++kt) {
        const unsigned short* Sb = S + (kt & 1) * 32768;
        unsigned short*       Sn = S + ((kt & 1) ^ 1) * 32768;

        if (kt < 11) {
            load_lds16(pA00, Sn + d00);
            load_lds16(pA01, Sn + d01);
            load_lds16(pA10, Sn + 8192 + d00);
            load_lds16(pA11, Sn + 8192 + d01);
            asm volatile("s_waitcnt vmcnt(4)" ::: "memory");
        } else {
            asm volatile("s_waitcnt vmcnt(0)" ::: "memory");
        }
        __builtin_amdgcn_s_barrier();
#pragma unroll
        for (int n = 0; n < 4; ++n) {
            bf0[n] = *(const short8*)&Sb[bbase + n * 1024 + sw0];
            bf1[n] = *(const short8*)&Sb[bbase + n * 1024 + sw1];
        }
        READ_A(0)
        DO_MFMA(0)
        asm volatile("" ::: "memory");
        __builtin_amdgcn_s_barrier();

        READ_A(1)
        if (kt < 11) {
            load_lds16(pB00, Sn + 16384 + d00);
            load_lds16(pB01, Sn + 16384 + d01);
            load_lds16(pB10, Sn + 16384 + 8192 + d00);
            load_lds16(pB11, Sn + 16384 + 8192 + d01);
        }
        asm volatile("" ::: "memory");
        __builtin_amdgcn_s_barrier();
        DO_MFMA(1)
        asm volatile("" ::: "memory");
        __builtin_amdgcn_s_barrier();

        READ_A(2)
        asm volatile("" ::: "memory");
        __builtin_amdgcn_s_barrier();
        DO_MFMA(2)
        asm volatile("" ::: "memory");
        __builtin_amdgcn_s_barrier();

        READ_A(3)
        asm volatile("" ::: "memory");
        __builtin_amdgcn_s_barrier();
        DO_MFMA(3)
        asm volatile("" ::: "memory");
        __builtin_amdgcn_s_barrier();

        pA00 += 64; pA01 += 64; pA10 += 64; pA11 += 64;
        pB00 += 64; pB01 += 64; pB10 += 64; pB11 += 64;
    }

    __syncthreads();
    float bias[4];
#pragma unroll
    for (int n = 0; n < 4; ++n) bias[n] = benc[bn + wn * 64 + n * 16 + lrow];
    unsigned short* Cs = S;
#pragma unroll
    for (int m = 0; m < 8; ++m)
#pragma unroll
        for (int n = 0; n < 4; ++n)
#pragma unroll
            for (int q = 0; q < 4; ++q)
                Cs[(wm * 128 + m * 16 + l4 * 4 + q) * 256 + wn * 64 + n * 16 + lrow] =
                    (unsigned short)f2bf(acc[m][n][q] + bias[n]);
    __syncthreads();
#pragma unroll
    for (int it = 0; it < 16; ++it) {
        const int g = t + it * 512;
        const int row = g >> 5;
        const int c8 = (g & 31) * 8;
        const short8 v = *(const short8*)&Cs[row * 256 + c8];
        __builtin_nontemporal_store(v, (short8*)&Zb[(bm + row) * FDICT + bn + c8]);
    }
}

// ---------------- K2: stats + LN + bracketed bisection + classify ----------------
// 6 barriers on the (verified) fast path.  Threshold: Gaussian-quantile bracket
// [Vhat-h, Vhat+h] verified by a packed dual count, then 3 bisection steps
// (|T - V128| <= h/8 = 0.031 << BAND_M - 2e).  Any check failure -> full-range
// 12-iter bisection (block-uniform branch), so correctness never depends on the
// statistical assumption.  Zero-fill of the feature row at the kernel tail.
__global__ __launch_bounds__(1024) void topk_select(
    const unsigned short* __restrict__ Zb, const float* __restrict__ gamma,
    const float* __restrict__ beta, const float* __restrict__ gbinfo,
    int* __restrict__ sel_idx, float* __restrict__ sel_val,
    int* __restrict__ band_idx, int* __restrict__ cdef, int* __restrict__ nband,
    float* __restrict__ muarr, float* __restrict__ sinvarr,
    float* __restrict__ feat)
{
    __shared__ float    redf[32];
    __shared__ unsigned cacc[16];
    __shared__ unsigned scomp[2];

    const int t = threadIdx.x;
    const int w = t >> 6;
    const long r = blockIdx.x;

    if (t < 16) cacc[t] = 0u;
    if (t == 16) { scomp[0] = 0u; scomp[1] = 0u; }

    // ---- load row + stats ----
    unsigned u[32];
    float sum = 0.f, sumsq = 0.f;
    const short8* Z8 = (const short8*)(Zb + r * (size_t)FDICT);
#pragma unroll
    for (int q = 0; q < 4; ++q) {
        const short8 v = Z8[q * 1024 + t];
#pragma unroll
        for (int j = 0; j < 8; ++j) {
            const float f = bf2f(v[j]);
            u[q * 8 + j] = __float_as_uint(f);
            sum += f; sumsq += f * f;
        }
    }
#pragma unroll
    for (int o = 32; o > 0; o >>= 1) {
        sum   += __shfl_down(sum, o, 64);
        sumsq += __shfl_down(sumsq, o, 64);
    }
    if ((t & 63) == 0) { redf[w] = sum; redf[16 + w] = sumsq; }
    __syncthreads();                                          // B1
    float s_ = 0.f, sq_ = 0.f;
#pragma unroll
    for (int i = 0; i < 16; ++i) { s_ += redf[i]; sq_ += redf[16 + i]; }
    const float mu = s_ / (float)FDICT;
    float var = sq_ / (float)FDICT - mu * mu;
    if (var < 0.f) var = 0.f;
    const float sinv = 1.f / sqrtf(var + LN_EPS);

    const float g0 = gbinfo[3], b0 = gbinfo[4];
    const bool uniform = (gbinfo[2] != 0.f) && (g0 > 0.f) && (g0 <= 2.f);

    // ---- normalize in registers ----
    if (uniform) {
        const float gs = sinv * g0;
#pragma unroll
        for (int i = 0; i < 32; ++i)
            u[i] = __float_as_uint(fmaxf(
                fmaf(__uint_as_float(u[i]) - mu, gs, b0), 0.f));
    } else {
#pragma unroll
        for (int q = 0; q < 4; ++q) {
            const size_t base = (size_t)(q * 1024 + t) * 8;
            const float4 g4a = *(const float4*)(gamma + base);
            const float4 g4b = *(const float4*)(gamma + base + 4);
            const float4 b4a = *(const float4*)(beta + base);
            const float4 b4b = *(const float4*)(beta + base + 4);
            const float gs[8] = {g4a.x, g4a.y, g4a.z, g4a.w, g4b.x, g4b.y, g4b.z, g4b.w};
            const float bs[8] = {b4a.x, b4a.y, b4a.z, b4a.w, b4b.x, b4b.y, b4b.z, b4b.w};
#pragma unroll
            for (int j = 0; j < 8; ++j) {
                const int i = q * 8 + j;
                u[i] = __float_as_uint(fmaxf(
                    fmaf((__uint_as_float(u[i]) - mu) * sinv, gs[j], bs[j]), 0.f));
            }
        }
    }

    // ---- threshold search ----
    float Tf = 0.f;
    bool got = false;
    int nextacc = 0;
    if (uniform) {
        const float Vh = fmaf(2.6601f, g0, b0);   // Phi^-1(1 - 128/32768) scaled
        const float h  = 0.25f * g0;
        float lo = Vh - h, hi = Vh + h;
        unsigned pc = 0;
#pragma unroll
        for (int i = 0; i < 32; ++i) {
            const float a = __uint_as_float(u[i]);
            pc += (a > lo) ? 1u : 0u;
            pc += (a > hi) ? 0x10000u : 0u;
        }
#pragma unroll
        for (int o = 32; o > 0; o >>= 1) pc += __shfl_down(pc, o, 64);
        if ((t & 63) == 0) atomicAdd(&cacc[0], pc);
        __syncthreads();                                      // B2
        const unsigned clo = cacc[0] & 0xFFFFu, chi = cacc[0] >> 16;
        if (clo >= TOPK && chi < TOPK) {
#pragma unroll 1
            for (int it = 1; it <= 3; ++it) {
                const float thr = 0.5f * (lo + hi);
                unsigned cnt = 0;
#pragma unroll
                for (int i = 0; i < 32; ++i)
                    cnt += (__uint_as_float(u[i]) > thr) ? 1u : 0u;
#pragma unroll
                for (int o = 32; o > 0; o >>= 1) cnt += __shfl_down(cnt, o, 64);
                if ((t & 63) == 0) atomicAdd(&cacc[it], cnt);
                __syncthreads();                              // B3-B5
                if (cacc[it] >= TOPK) lo = thr; else hi = thr;
            }
            Tf = 0.5f * (lo + hi);
            got = true;
        }
        nextacc = 4;
    }
    if (!got) {
        // fallback: full-range 12-iter bisection (cold path, block-uniform)
        __syncthreads();                      // protect redf reuse
        float vmax = 0.f;
#pragma unroll
        for (int i = 0; i < 32; ++i) vmax = fmaxf(vmax, __uint_as_float(u[i]));
#pragma unroll
        for (int o = 32; o > 0; o >>= 1) vmax = fmaxf(vmax, __shfl_down(vmax, o, 64));
        if ((t & 63) == 0) redf[w] = vmax;
        __syncthreads();
        float mx = 0.f;
#pragma unroll
        for (int i = 0; i < 16; ++i) mx = fmaxf(mx, redf[i]);
        float lo = 0.f, hi = mx + 1e-6f;
#pragma unroll 1
        for (int it = 0; it < 12; ++it) {
            const float thr = 0.5f * (lo + hi);
            unsigned cnt = 0;
#pragma unroll
            for (int i = 0; i < 32; ++i)
                cnt += (__uint_as_float(u[i]) > thr) ? 1u : 0u;
#pragma unroll
            for (int o = 32; o > 0; o >>= 1) cnt += __shfl_down(cnt, o, 64);
            if ((t & 63) == 0) atomicAdd(&cacc[nextacc + it], cnt);
            __syncthreads();
            if (cacc[nextacc + it] >= TOPK) lo = thr; else hi = thr;
        }
        Tf = 0.5f * (lo + hi);
    }

    const float thi = Tf + BAND_M, tlo = Tf - BAND_M;

    // ---- classify (feat scatter deferred to refine_select) ----
#pragma unroll
    for (int i = 0; i < 32; ++i) {
        const float a = __uint_as_float(u[i]);
        const int idx = ((i >> 3) * 1024 + t) * 8 + (i & 7);
        if (a > thi) {
            const unsigned s2 = atomicAdd(&scomp[0], 1u);
            sel_idx[r * TOPK + s2] = idx;
            sel_val[r * TOPK + s2] = a;
        } else if (a >= tlo) {
            const unsigned s2 = atomicAdd(&scomp[1], 1u);
            if (s2 < BAND_CAP) band_idx[r * BAND_CAP + s2] = idx;
        }
    }
    __syncthreads();                                          // B6 (last)
    if (t == 0) {
        cdef[r]  = (int)scomp[0];
        int nb = (int)scomp[1]; if (nb > BAND_CAP) nb = BAND_CAP;
        nband[r] = nb;
        muarr[r] = mu; sinvarr[r] = sinv;
    }
    // tail: zero the feature row; no barrier follows -> retires asynchronously
    if (feat) {
        const f32x4 z4 = (f32x4){0.f, 0.f, 0.f, 0.f};
        f32x4* row4 = (f32x4*)(feat + r * (size_t)FDICT);
#pragma unroll
        for (int q = 0; q < 8; ++q)
            __builtin_nontemporal_store(z4, &row4[q * 1024 + t]);
    }
}

// ---------------- K2b: fp64 refinement + final select + feat scatter ------------
__global__ __launch_bounds__(256) void refine_select(
    const float* __restrict__ X, const float* __restrict__ Wenc,
    const float* __restrict__ benc, const float* __restrict__ gamma,
    const float* __restrict__ beta, const int* __restrict__ band_idx,
    const int* __restrict__ cdef, const int* __restrict__ nband,
    const float* __restrict__ muarr, const float* __restrict__ sinvarr,
    int* __restrict__ sel_idx, float* __restrict__ sel_val,
    float* __restrict__ feat)
{
    __shared__ float xs[DIM];
    __shared__ float cval[BAND_CAP];
    __shared__ int   cidx[BAND_CAP];
    __shared__ int   scnt;
    const int t = threadIdx.x;
    const long r = blockIdx.x;
    const int w = t >> 6, l = t & 63;

    for (int i = t; i < DIM; i += 256) xs[i] = X[r * DIM + i];
    if (t == 0) scnt = 0;
    const int nb = nband[r];
    const int cd = cdef[r];
    int need = TOPK - cd; if (need > nb) need = nb;
    const double mu = (double)muarr[r], sinv = (double)sinvarr[r];

    // scatter the definite-in values (zeros were written by topk's tail;
    // kernel boundary orders them before us)
    if (feat && t < cd)
        feat[r * (size_t)FDICT + sel_idx[r * TOPK + t]] = sel_val[r * TOPK + t];
    __syncthreads();

    for (int c = w; c < nb; c += 4) {
        const int fi = band_idx[r * BAND_CAP + c];
        const float* wr = Wenc + (size_t)fi * DIM;
        double s = 0.0;
        for (int k = l; k < DIM; k += 64) s = fma((double)xs[k], (double)wr[k], s);
#pragma unroll
        for (int o = 32; o > 0; o >>= 1) s += __shfl_down(s, o, 64);
        if (l == 0) {
            const double z = s + (double)benc[fi];
            const double a = (z - mu) * sinv * (double)gamma[fi] + (double)beta[fi];
            cval[c] = fmaxf((float)a, 0.f);
            cidx[c] = fi;
        }
    }
    __syncthreads();
    if (t < nb) {
        const float v = cval[t];
        const int id = cidx[t];
        int rank = 0;
        for (int j = 0; j < nb; ++j) {
            const float vj = cval[j];
            rank += (vj > v) || (vj == v && cidx[j] < id);
        }
        if (rank < need) {
            const int s = atomicAdd(&scnt, 1);
            sel_idx[r * TOPK + cd + s] = id;
            sel_val[r * TOPK + cd + s] = v;
            if (feat) feat[r * (size_t)FDICT + id] = v;
        }
    }
}

// ---------------- K3: transpose W_dec [768][32768] -> WdTb [32768][768] bf16 ----
__global__ __launch_bounds__(256) void transposeWd(
    const float* __restrict__ Wd, unsigned short* __restrict__ WdTb)
{
    __shared__ float tile[32][33];
    const int fx = blockIdx.x * 32;
    const int dy = blockIdx.y * 32;
    const int tx = threadIdx.x & 31;
    const int ty = threadIdx.x >> 5;
    for (int i = ty; i < 32; i += 8)
        tile[i][tx] = Wd[(size_t)(dy + i) * FDICT + fx + tx];
    __syncthreads();
    for (int i = ty; i < 32; i += 8)
        WdTb[(size_t)(fx + i) * DIM + dy + tx] = (unsigned short)f2bf(tile[tx][i]);
}

// ---------------- K4: sparse decode (bf16 W_decT, fp32 math) --------------------
__global__ __launch_bounds__(384) void decode(
    const int* __restrict__ sel_idx, const float* __restrict__ sel_val,
    const unsigned short* __restrict__ WdTb, const float* __restrict__ bdec,
    float* __restrict__ out)
{
    __shared__ int   sidx[TOPK];
    __shared__ float sval[TOPK];
    const int t = threadIdx.x;
    const long r = blockIdx.x;
    if (t < TOPK) { sidx[t] = sel_idx[r * TOPK + t]; sval[t] = sel_val[r * TOPK + t]; }
    __syncthreads();
    const float2 b2 = *(const float2*)(bdec + t * 2);
    float a0 = b2.x, a1 = b2.y;
    for (int j = 0; j < TOPK; ++j) {
        const unsigned wp = *(const unsigned*)(WdTb + (size_t)sidx[j] * DIM + t * 2);
        const float v = sval[j];
        a0 = fmaf(v, __uint_as_float((wp & 0xFFFFu) << 16), a0);
        a1 = fmaf(v, __uint_as_float(wp & 0xFFFF0000u), a1);
    }
    float2 o2; o2.x = a0; o2.y = a1;
    *(float2*)(out + r * DIM + t * 2) = o2;
}

// ---------------- K5 (fallback only): zero rows + scatter -----------------------
__global__ __launch_bounds__(1024) void featfill(
    const int* __restrict__ sel_idx, const float* __restrict__ sel_val,
    float* __restrict__ feat)
{
    const int t = threadIdx.x;
    const long r = blockIdx.x;
    const f32x4 z4 = (f32x4){0.f, 0.f, 0.f, 0.f};
    f32x4* row4 = (f32x4*)(feat + r * FDICT);
    for (int i = t; i < FDICT / 4; i += 1024)
        __builtin_nontemporal_store(z4, &row4[i]);
    __syncthreads();
    if (t < TOPK)
        feat[r * FDICT + sel_idx[r * TOPK + t]] = sel_val[r * TOPK + t];
}

extern "C" void kernel_launch(void* const* d_in, const int* in_sizes, int n_in,
                              void* d_out, int out_size, void* d_ws, size_t ws_size,
                              hipStream_t stream)
{
    const float* x     = (const float*)d_in[0];
    const float* Wenc  = (const float*)d_in[1];
    const float* benc  = (const float*)d_in[2];
    const float* gamma = (const float*)d_in[3];
    const float* beta  = (const float*)d_in[4];
    const float* Wdec  = (const float*)d_in[5];
    const float* bdec  = (const float*)d_in[6];

    float* out  = (float*)d_out;                      // [8192*768] fp32
    float* feat = out + (size_t)R_TOT * DIM;          // [8192*32768] fp32 region

    unsigned short* Xb = (unsigned short*)out;        // 12.6 MB (dead until decode)

    char* ws = (char*)d_ws;
    int*   sidx  = (int*)ws;                                        // 4 MB
    float* sval  = (float*)(ws + (size_t)R_TOT * TOPK * 4);         // 4 MB
    int*   bidx  = (int*)(ws + (size_t)R_TOT * TOPK * 8);           // 6.3 MB
    int*   cdef  = (int*)(ws + (size_t)R_TOT * (TOPK * 8 + BAND_CAP * 4));
    int*   nbnd  = cdef + R_TOT;
    float* muarr = (float*)(nbnd + R_TOT);
    float* sinva = muarr + R_TOT;
    float* gbinfo = sinva + R_TOT;                                  // 8 floats

    // big-workspace path: Zb/Wb/WdTb live in ws -> feat region free during topk
    const size_t WS_NEED = 624ull << 20;
    const bool big = (ws_size >= WS_NEED);

    unsigned short* Zb, *Wb, *WdTb;
    if (big) {
        Zb   = (unsigned short*)(ws + (16ull << 20));
        Wb   = (unsigned short*)(ws + (528ull << 20));
        WdTb = (unsigned short*)(ws + (576ull << 20));
    } else {
        Zb   = (unsigned short*)feat;                            // 537 MB
        Wb   = (unsigned short*)((char*)feat + 536870912ull);    // 50.3 MB
        WdTb = (unsigned short*)((char*)feat + 587202560ull);    // 50.3 MB
    }
    float* featArg = big ? feat : nullptr;

    prep_gb<<<1, 256, 0, stream>>>(gamma, beta, gbinfo);
    conv_bf16<<<1536, 256, 0, stream>>>(x,    Xb, R_TOT * DIM / 8);
    conv_bf16<<<2048, 256, 0, stream>>>(Wenc, Wb, FDICT * DIM / 8);
    enc_gemm<<<4096, 512, 0, stream>>>(Xb, Wb, benc, Zb);
    topk_select<<<R_TOT, 1024, 0, stream>>>(Zb, gamma, beta, gbinfo,
                                            sidx, sval, bidx, cdef, nbnd,
                                            muarr, sinva, featArg);
    refine_select<<<R_TOT, 256, 0, stream>>>(x, Wenc, benc, gamma, beta,
                                             bidx, cdef, nbnd, muarr, sinva,
                                             sidx, sval, featArg);
    transposeWd<<<dim3(FDICT / 32, DIM / 32), 256, 0, stream>>>(Wdec, WdTb);
    decode<<<R_TOT, 384, 0, stream>>>(sidx, sval, WdTb, bdec, out);
    if (!big)
        featfill<<<R_TOT, 1024, 0, stream>>>(sidx, sval, feat);
}